// Round 7
// baseline (289.772 us; speedup 1.0000x reference)
//
#include <hip/hip_runtime.h>

// MHA forward, MI355X gfx950. B=4 D=1024 S=2048 H=16 hd=64.
// R6: attn occupancy 2->4 waves/SIMD. q_w=32, 128-q blocks, grid (64,16)=1024
// blocks = 4/CU (LDS 32KB, VGPR<=128 via launch_bounds(256,4)). Register-PV
// retained (K=16 PV MFMA, no P LDS). jk->exp->PV fused (short pb live range).
// Grid x=64 (=0 mod 8) pins each head to one XCD (R5 measured FETCH 25 MB).

typedef __bf16 bf16;
typedef __attribute__((ext_vector_type(8))) __bf16 bf16x8;
typedef __attribute__((ext_vector_type(4))) __bf16 bf16x4;
typedef __attribute__((ext_vector_type(4))) float f32x4;
typedef __attribute__((ext_vector_type(4))) short s16x4;

#define NB 4
#define ND 1024
#define NS 2048
#define NH 16
#define NM 8192  // NB*NS

__device__ __forceinline__ void gld16(const void* g, void* l) {
  __builtin_amdgcn_global_load_lds((__attribute__((address_space(1))) void*)g,
                                   (__attribute__((address_space(3))) void*)l, 16, 0, 0);
}

__device__ __forceinline__ int swz4(int r) { return (r + (r >> 2)) & 3; }

__device__ __forceinline__ float exp2_fast(float x) {
#if __has_builtin(__builtin_amdgcn_exp2f)
  return __builtin_amdgcn_exp2f(x);
#else
  return exp2f(x);
#endif
}

// ===================== prep_x: xT[b*S+s][d] = bf16(x[b][d][s] + PE[d][s]) ===
__global__ __launch_bounds__(256) void prep_x_kernel(const float* __restrict__ x,
                                                     bf16* __restrict__ xT) {
  __shared__ float t[32][33];
  const int tx = threadIdx.x, ty = threadIdx.y;
  const int s0 = blockIdx.x * 32, d0 = blockIdx.y * 32, b = blockIdx.z;
#pragma unroll
  for (int i = 0; i < 4; ++i) {
    const int rr = ty + i * 8;
    const int d = d0 + rr, s = s0 + tx;
    const float freq = __expf(-(float)(d >> 1) * 0.01798894603980689f);
    const float ang = (float)s * freq;
    const float pe = (d & 1) ? cosf(ang) : sinf(ang);  // precise: ang up to 2047 rad
    t[rr][tx] = x[((size_t)b * ND + d) * NS + s] + pe;
  }
  __syncthreads();
#pragma unroll
  for (int i = 0; i < 4; ++i) {
    const int a = ty + i * 8;  // s offset
    xT[((size_t)b * NS + s0 + a) * ND + d0 + tx] = (bf16)t[tx][a];
  }
}

// ===================== prep_w: Wq|Wk|Wv -> Wqkv bf16 [3072][1024]; Wo -> bf16
__global__ __launch_bounds__(256) void prep_w_kernel(const float* __restrict__ Wq,
                                                     const float* __restrict__ Wk,
                                                     const float* __restrict__ Wv,
                                                     const float* __restrict__ Wo,
                                                     bf16* __restrict__ Wqkv,
                                                     bf16* __restrict__ WoB) {
  const size_t t = (size_t)blockIdx.x * blockDim.x + threadIdx.x;
  const size_t i = t * 4;
  const float* src;
  bf16* dst;
  size_t off;
  if (i < (size_t)3 * 1024 * 1024) {
    const int sel = (int)(i >> 20);
    src = sel == 0 ? Wq : (sel == 1 ? Wk : Wv);
    off = i - ((size_t)sel << 20);
    dst = Wqkv + i;
  } else {
    src = Wo;
    off = i - ((size_t)3 << 20);
    dst = WoB + off;
  }
  const f32x4 v = *(const f32x4*)(src + off);
  bf16x4 o;
  o[0] = (bf16)v[0];
  o[1] = (bf16)v[1];
  o[2] = (bf16)v[2];
  o[3] = (bf16)v[3];
  *(bf16x4*)dst = o;
}

// ===================== shared 128x128 GEMM mainloop (A [M,K], B [N,K], K=1024)
__device__ __forceinline__ void gemm_tile_128(const bf16* __restrict__ A,
                                              const bf16* __restrict__ Bm,
                                              int tm, int tn, bf16* ldsA, bf16* ldsB,
                                              f32x4 acc[4][4]) {
  const int tid = threadIdx.x;
  const int lane = tid & 63, wave = tid >> 6;
  const int wm = wave >> 1, wn = wave & 1;
  const int rl = lane & 15, quad = lane >> 4;
  const int sw = swz4(rl);
  int r0[2], c0[2], ld0[2];
#pragma unroll
  for (int j = 0; j < 2; ++j) {
    const int chunk = wave * 2 + j;
    const int o = chunk * 1024 + lane * 16;  // physical byte offset in 8KB tile
    const int r = o >> 6;                    // row (64B rows)
    r0[j] = r;
    c0[j] = (((o >> 4) & 3) ^ swz4(r)) * 8;  // logical element col (XOR swizzle)
    ld0[j] = chunk * 1024;                   // wave-uniform LDS window base
  }
  for (int kt = 0; kt < 1024; kt += 32) {
#pragma unroll
    for (int j = 0; j < 2; ++j) {
      gld16(A + (size_t)(tm + r0[j]) * 1024 + kt + c0[j], (char*)ldsA + ld0[j]);
      gld16(Bm + (size_t)(tn + r0[j]) * 1024 + kt + c0[j], (char*)ldsB + ld0[j]);
    }
    __syncthreads();
    bf16x8 af[4], bfr[4];
#pragma unroll
    for (int i = 0; i < 4; ++i) {
      const int ra = wm * 64 + i * 16 + rl;
      af[i] = *(const bf16x8*)((const char*)ldsA + ra * 64 + ((quad ^ sw) * 16));
      const int rb = wn * 64 + i * 16 + rl;
      bfr[i] = *(const bf16x8*)((const char*)ldsB + rb * 64 + ((quad ^ sw) * 16));
    }
#pragma unroll
    for (int i = 0; i < 4; ++i)
#pragma unroll
      for (int j = 0; j < 4; ++j)
        acc[i][j] = __builtin_amdgcn_mfma_f32_16x16x32_bf16(af[i], bfr[j], acc[i][j], 0, 0, 0);
    __syncthreads();
  }
}

// ===================== QKV projection GEMM ==================================
__global__ __launch_bounds__(256, 2) void gemm_qkv_kernel(
    const bf16* __restrict__ xT, const bf16* __restrict__ Wqkv,
    const float* __restrict__ bq, const float* __restrict__ bk,
    const float* __restrict__ bv, bf16* __restrict__ Q, bf16* __restrict__ Kb,
    bf16* __restrict__ VT) {
  __shared__ bf16 ldsA[128 * 32], ldsB[128 * 32];
  const int tm = blockIdx.x * 128, tn = blockIdx.y * 128;
  f32x4 acc[4][4];
  const f32x4 z = {0.f, 0.f, 0.f, 0.f};
#pragma unroll
  for (int i = 0; i < 4; ++i)
#pragma unroll
    for (int j = 0; j < 4; ++j) acc[i][j] = z;
  gemm_tile_128(xT, Wqkv, tm, tn, ldsA, ldsB, acc);
  const int lane = threadIdx.x & 63, wave = threadIdx.x >> 6;
  const int wm = wave >> 1, wn = wave & 1;
  const int rl = lane & 15, quad = lane >> 4;
  // Q scale folds 1/sqrt(64) * log2(e) so attn uses raw 2^x
  const float QSCALE = 0.18033688011112042f;
#pragma unroll
  for (int j = 0; j < 4; ++j) {
    const int n = tn + wn * 64 + j * 16 + rl;  // 0..3071
    const int which = n >> 10;                 // uniform per block
    const int nl = n & 1023;
    const int h = nl >> 6, d = nl & 63;
    const float bias = (which == 0 ? bq : which == 1 ? bk : bv)[nl];
#pragma unroll
    for (int i = 0; i < 4; ++i) {
      const int m0 = tm + wm * 64 + i * 16 + quad * 4;
      const int b = m0 >> 11, s0 = m0 & 2047;
      const size_t bh = (size_t)(b * 16 + h);
      if (which == 2) {
        bf16x4 pk;
#pragma unroll
        for (int r = 0; r < 4; ++r) pk[r] = (bf16)(acc[i][j][r] + bias);
        *(bf16x4*)(VT + ((size_t)bh * 64 + d) * 2048 + s0) = pk;  // V^T packed
      } else {
#pragma unroll
        for (int r = 0; r < 4; ++r) {
          const float v = acc[i][j][r] + bias;
          const int s = s0 + r;
          if (which == 0)
            Q[(bh * 2048 + s) * 64 + d] = (bf16)(v * QSCALE);
          else
            Kb[(bh * 2048 + s) * 64 + d] = (bf16)v;
        }
      }
    }
  }
}

// ===================== flash attention ======================================
// grid (B*H, S/128): x=64 (=0 mod 8) pins each head to one XCD. 128 q/block,
// 32 q/wave, 4 blocks/CU (32 KB LDS, 4 waves/SIMD). Q direct to VGPRs.
// K/V double-buffered LDS. S^T = K*Q^T (16x16x32); P^T = exp(S^T) stays in
// registers, feeds 16x16x16 PV as B operand. jk->exp->PV fused.
__global__ __launch_bounds__(256, 4) void attn_kernel(const bf16* __restrict__ Q,
                                                      const bf16* __restrict__ Kb,
                                                      const bf16* __restrict__ VT,
                                                      bf16* __restrict__ AO) {
  __shared__ __align__(16) char smem[32768];
  char* ldsK = smem;          // 2 x 8 KB (double buffer)
  char* ldsV = smem + 16384;  // 2 x 8 KB (double buffer)
  const int tid = threadIdx.x;
  const int lane = tid & 63, wave = tid >> 6;
  const int rl = lane & 15, quad = lane >> 4;
  const int bh = blockIdx.x;
  const int q0 = blockIdx.y * 128 + wave * 32;
  const bf16* Qb = Q + ((size_t)bh * 2048 + q0) * 64;
  const bf16* Kbb = Kb + (size_t)bh * 2048 * 64;
  const bf16* Vb = VT + (size_t)bh * 64 * 2048;
  // staging geometry (shared by K and V): 2 x 16B chunks per thread per buffer
  const int o0 = wave * 1024 + lane * 16, o1 = o0 + 4096;
  const int ra = o0 >> 7, rb = o1 >> 7;
  const int ca = (((o0 >> 4) & 7) ^ (ra & 7)) * 16;
  const int cb = (((o1 >> 4) & 7) ^ (rb & 7)) * 16;
  gld16((const char*)Kbb + (size_t)ra * 128 + ca, ldsK + wave * 1024);
  gld16((const char*)Kbb + (size_t)rb * 128 + cb, ldsK + wave * 1024 + 4096);
  gld16((const char*)Vb + (size_t)ra * 4096 + ca, ldsV + wave * 1024);
  gld16((const char*)Vb + (size_t)rb * 4096 + cb, ldsV + wave * 1024 + 4096);
  // Q fragments straight from global (read exactly once; aligned 16B)
  bf16x8 qf[2][2];
#pragma unroll
  for (int i = 0; i < 2; ++i)
#pragma unroll
    for (int ks = 0; ks < 2; ++ks)
      qf[i][ks] = *(const bf16x8*)(Qb + (i * 16 + rl) * 64 + ks * 32 + quad * 8);
  f32x4 o_acc[4][2];  // [dt][qt] — O^T tiles: rows d, cols q
  f32x4 l4[2];        // per-lane quad-partial row sums, per q-tile
  const f32x4 z = {0.f, 0.f, 0.f, 0.f};
#pragma unroll
  for (int dt = 0; dt < 4; ++dt) {
    o_acc[dt][0] = z;
    o_acc[dt][1] = z;
  }
  l4[0] = z;
  l4[1] = z;
  int buf = 0;
  for (int kt = 0; kt < 2048; kt += 64, buf ^= 1) {
    __syncthreads();  // K/V[buf] landed (vmcnt drain); buf^1 free for prefetch
    if (kt + 64 < 2048) {
      const int nb = (buf ^ 1) * 8192;
      gld16((const char*)Kbb + (size_t)(kt + 64 + ra) * 128 + ca, ldsK + nb + wave * 1024);
      gld16((const char*)Kbb + (size_t)(kt + 64 + rb) * 128 + cb,
            ldsK + nb + wave * 1024 + 4096);
      gld16((const char*)Vb + (size_t)ra * 4096 + (size_t)(kt + 64) * 2 + ca,
            ldsV + nb + wave * 1024);
      gld16((const char*)Vb + (size_t)rb * 4096 + (size_t)(kt + 64) * 2 + cb,
            ldsV + nb + wave * 1024 + 4096);
    }
    const char* Kbase = ldsK + buf * 8192;
    const char* Vbase = ldsV + buf * 8192;
#pragma unroll
    for (int jk = 0; jk < 4; ++jk) {
      // S^T tile: keys jk*16+quad*4+r (rows), q = qt*16+rl (cols)
      const bf16x8 kf0 =
          *(const bf16x8*)(Kbase + (jk * 16 + rl) * 128 + ((quad ^ (rl & 7)) * 16));
      const bf16x8 kf1 =
          *(const bf16x8*)(Kbase + (jk * 16 + rl) * 128 + (((4 + quad) ^ (rl & 7)) * 16));
      f32x4 s0 = z, s1 = z;
      s0 = __builtin_amdgcn_mfma_f32_16x16x32_bf16(kf0, qf[0][0], s0, 0, 0, 0);
      s1 = __builtin_amdgcn_mfma_f32_16x16x32_bf16(kf0, qf[1][0], s1, 0, 0, 0);
      s0 = __builtin_amdgcn_mfma_f32_16x16x32_bf16(kf1, qf[0][1], s0, 0, 0, 0);
      s1 = __builtin_amdgcn_mfma_f32_16x16x32_bf16(kf1, qf[1][1], s1, 0, 0, 0);
      // P^T fragments in regs: exp + pack; B-operand k = quad*4+r matches rows
      f32x4 e0, e1;
#pragma unroll
      for (int r = 0; r < 4; ++r) e0[r] = exp2_fast(s0[r]);
#pragma unroll
      for (int r = 0; r < 4; ++r) e1[r] = exp2_fast(s1[r]);
      l4[0] += e0;
      l4[1] += e1;
      bf16x4 p0, p1;
#pragma unroll
      for (int r = 0; r < 4; ++r) p0[r] = (bf16)e0[r];
#pragma unroll
      for (int r = 0; r < 4; ++r) p1[r] = (bf16)e1[r];
      const s16x4 pb0 = __builtin_bit_cast(s16x4, p0);
      const s16x4 pb1 = __builtin_bit_cast(s16x4, p1);
      // O^T += V^T P^T for this 16-key group (ki == jk)
#pragma unroll
      for (int dt = 0; dt < 4; ++dt) {
        const s16x4 vf = *(const s16x4*)(Vbase + (dt * 16 + rl) * 128 +
                                         (((jk * 2 + (quad >> 1)) ^ (rl & 7)) * 16) +
                                         (quad & 1) * 8);
        o_acc[dt][0] =
            __builtin_amdgcn_mfma_f32_16x16x16bf16_1k(vf, pb0, o_acc[dt][0], 0, 0, 0);
        o_acc[dt][1] =
            __builtin_amdgcn_mfma_f32_16x16x16bf16_1k(vf, pb1, o_acc[dt][1], 0, 0, 0);
      }
    }
  }
  // epilogue: l = butterfly over quads; O^T C-layout -> 4 consecutive d per lane
  const int b = bh >> 4, h = bh & 15;
#pragma unroll
  for (int qt = 0; qt < 2; ++qt) {
    float s = l4[qt][0] + l4[qt][1] + l4[qt][2] + l4[qt][3];
    s += __shfl_xor(s, 16);
    s += __shfl_xor(s, 32);
    const float linv = __builtin_amdgcn_rcpf(s);
    const size_t row = ((size_t)b * 2048 + q0 + qt * 16 + rl) * 1024;
#pragma unroll
    for (int dt = 0; dt < 4; ++dt) {
      bf16x4 ov;
#pragma unroll
      for (int r = 0; r < 4; ++r) ov[r] = (bf16)(o_acc[dt][qt][r] * linv);
      *(bf16x4*)(AO + row + h * 64 + dt * 16 + quad * 4) = ov;
    }
  }
}

// ===================== output projection GEMM (transposed fp32 store) =======
__global__ __launch_bounds__(256, 2) void gemm_out_kernel(const bf16* __restrict__ AO,
                                                          const bf16* __restrict__ WoB,
                                                          const float* __restrict__ bo,
                                                          float* __restrict__ out) {
  __shared__ bf16 ldsA[128 * 32], ldsB[128 * 32];
  const int tm = blockIdx.x * 128, tn = blockIdx.y * 128;
  f32x4 acc[4][4];
  const f32x4 z = {0.f, 0.f, 0.f, 0.f};
#pragma unroll
  for (int i = 0; i < 4; ++i)
#pragma unroll
    for (int j = 0; j < 4; ++j) acc[i][j] = z;
  gemm_tile_128(AO, WoB, tm, tn, ldsA, ldsB, acc);
  const int lane = threadIdx.x & 63, wave = threadIdx.x >> 6;
  const int wm = wave >> 1, wn = wave & 1;
  const int rl = lane & 15, quad = lane >> 4;
#pragma unroll
  for (int j = 0; j < 4; ++j) {
    const int n = tn + wn * 64 + j * 16 + rl;  // = d
    const float bias = bo[n];
#pragma unroll
    for (int i = 0; i < 4; ++i) {
      const int m0 = tm + wm * 64 + i * 16 + quad * 4;
      const int b = m0 >> 11, s = m0 & 2047;
      f32x4 v = acc[i][j];
      v[0] += bias;
      v[1] += bias;
      v[2] += bias;
      v[3] += bias;
      *(f32x4*)(out + ((size_t)(b * 1024 + n)) * 2048 + s) = v;
    }
  }
}

extern "C" void kernel_launch(void* const* d_in, const int* in_sizes, int n_in,
                              void* d_out, int out_size, void* d_ws, size_t ws_size,
                              hipStream_t stream) {
  const float* x = (const float*)d_in[0];
  const float* Wq = (const float*)d_in[1];
  const float* bq = (const float*)d_in[2];
  const float* Wk = (const float*)d_in[3];
  const float* bk = (const float*)d_in[4];
  const float* Wv = (const float*)d_in[5];
  const float* bv = (const float*)d_in[6];
  const float* Wo = (const float*)d_in[7];
  const float* bo = (const float*)d_in[8];
  float* out = (float*)d_out;

  char* p = (char*)d_ws;
  bf16* xT = (bf16*)p;
  p += (size_t)NM * ND * 2;  // 16 MiB
  bf16* Wqkv = (bf16*)p;
  p += (size_t)3 * ND * ND * 2;  // 6 MiB
  bf16* WoB = (bf16*)p;
  p += (size_t)ND * ND * 2;  // 2 MiB
  bf16* Qb = (bf16*)p;
  p += (size_t)NM * ND * 2;
  bf16* Kbf = (bf16*)p;
  p += (size_t)NM * ND * 2;
  bf16* VTb = (bf16*)p;
  p += (size_t)NM * ND * 2;
  bf16* AO = xT;  // alias: xT fully consumed by gemm_qkv before attn writes AO

  prep_x_kernel<<<dim3(NS / 32, ND / 32, NB), dim3(32, 8), 0, stream>>>(x, xT);
  prep_w_kernel<<<dim3(4096), dim3(256), 0, stream>>>(Wq, Wk, Wv, Wo, Wqkv, WoB);
  gemm_qkv_kernel<<<dim3(NM / 128, 3072 / 128), dim3(256), 0, stream>>>(
      xT, Wqkv, bq, bk, bv, Qb, Kbf, VTb);
  attn_kernel<<<dim3(NB * NH, NS / 128), dim3(256), 0, stream>>>(Qb, Kbf, VTb, AO);
  gemm_out_kernel<<<dim3(NM / 128, ND / 128), dim3(256), 0, stream>>>(AO, WoB, bo, out);
}

// Round 8
// 271.163 us; speedup vs baseline: 1.0686x; 1.0686x over previous
//
#include <hip/hip_runtime.h>

// MHA forward, MI355X gfx950. B=4 D=1024 S=2048 H=16 hd=64.
// R7: attn = R4 structure (all-K=32 MFMA, P via per-wave LDS) with the two
// measured fixes: bh-on-x grid (FETCH 25 MB, R5) and chunk^(rl&7) P swizzle
// (R4's P-write was a real 16-way conflict: word offset independent of rl).
// GEMMs: BK=64 (16 KB tiles, 128B rows) — halves barrier drains on K=1024.

typedef __bf16 bf16;
typedef __attribute__((ext_vector_type(8))) __bf16 bf16x8;
typedef __attribute__((ext_vector_type(4))) __bf16 bf16x4;
typedef __attribute__((ext_vector_type(4))) float f32x4;

#define NB 4
#define ND 1024
#define NS 2048
#define NH 16
#define NM 8192  // NB*NS

__device__ __forceinline__ void gld16(const void* g, void* l) {
  __builtin_amdgcn_global_load_lds((__attribute__((address_space(1))) void*)g,
                                   (__attribute__((address_space(3))) void*)l, 16, 0, 0);
}

__device__ __forceinline__ float exp2_fast(float x) {
#if __has_builtin(__builtin_amdgcn_exp2f)
  return __builtin_amdgcn_exp2f(x);
#else
  return exp2f(x);
#endif
}

// ===================== prep_x: xT[b*S+s][d] = bf16(x[b][d][s] + PE[d][s]) ===
__global__ __launch_bounds__(256) void prep_x_kernel(const float* __restrict__ x,
                                                     bf16* __restrict__ xT) {
  __shared__ float t[32][33];
  const int tx = threadIdx.x, ty = threadIdx.y;
  const int s0 = blockIdx.x * 32, d0 = blockIdx.y * 32, b = blockIdx.z;
#pragma unroll
  for (int i = 0; i < 4; ++i) {
    const int rr = ty + i * 8;
    const int d = d0 + rr, s = s0 + tx;
    const float freq = __expf(-(float)(d >> 1) * 0.01798894603980689f);
    const float ang = (float)s * freq;
    const float pe = (d & 1) ? cosf(ang) : sinf(ang);  // precise: ang up to 2047 rad
    t[rr][tx] = x[((size_t)b * ND + d) * NS + s] + pe;
  }
  __syncthreads();
#pragma unroll
  for (int i = 0; i < 4; ++i) {
    const int a = ty + i * 8;  // s offset
    xT[((size_t)b * NS + s0 + a) * ND + d0 + tx] = (bf16)t[tx][a];
  }
}

// ===================== prep_w: Wq|Wk|Wv -> Wqkv bf16 [3072][1024]; Wo -> bf16
__global__ __launch_bounds__(256) void prep_w_kernel(const float* __restrict__ Wq,
                                                     const float* __restrict__ Wk,
                                                     const float* __restrict__ Wv,
                                                     const float* __restrict__ Wo,
                                                     bf16* __restrict__ Wqkv,
                                                     bf16* __restrict__ WoB) {
  const size_t t = (size_t)blockIdx.x * blockDim.x + threadIdx.x;
  const size_t i = t * 4;
  const float* src;
  bf16* dst;
  size_t off;
  if (i < (size_t)3 * 1024 * 1024) {
    const int sel = (int)(i >> 20);
    src = sel == 0 ? Wq : (sel == 1 ? Wk : Wv);
    off = i - ((size_t)sel << 20);
    dst = Wqkv + i;
  } else {
    src = Wo;
    off = i - ((size_t)3 << 20);
    dst = WoB + off;
  }
  const f32x4 v = *(const f32x4*)(src + off);
  bf16x4 o;
  o[0] = (bf16)v[0];
  o[1] = (bf16)v[1];
  o[2] = (bf16)v[2];
  o[3] = (bf16)v[3];
  *(bf16x4*)dst = o;
}

// ============ shared 128x128 GEMM mainloop, BK=64 (A [M,K], B [N,K], K=1024)
// Tiles 128 rows x 64 cols (16 KB, 128B rows), chunk^(row&7) XOR swizzle.
__device__ __forceinline__ void gemm_tile_128(const bf16* __restrict__ A,
                                              const bf16* __restrict__ Bm,
                                              int tm, int tn, bf16* ldsA, bf16* ldsB,
                                              f32x4 acc[4][4]) {
  const int tid = threadIdx.x;
  const int lane = tid & 63, wave = tid >> 6;
  const int wm = wave >> 1, wn = wave & 1;
  const int rl = lane & 15, quad = lane >> 4;
  int r0[4], c0[4];
#pragma unroll
  for (int j = 0; j < 4; ++j) {
    const int o = (wave * 4 + j) * 1024 + lane * 16;  // byte offset in 16KB tile
    const int r = o >> 7;                             // row (128B rows)
    r0[j] = r;
    c0[j] = ((((o >> 4) & 7) ^ (r & 7)) * 8);  // element col, XOR swizzled
  }
  for (int kt = 0; kt < 1024; kt += 64) {
#pragma unroll
    for (int j = 0; j < 4; ++j) {
      gld16(A + (size_t)(tm + r0[j]) * 1024 + kt + c0[j], (char*)ldsA + (wave * 4 + j) * 1024);
      gld16(Bm + (size_t)(tn + r0[j]) * 1024 + kt + c0[j], (char*)ldsB + (wave * 4 + j) * 1024);
    }
    __syncthreads();
#pragma unroll
    for (int kk = 0; kk < 2; ++kk) {
      bf16x8 af[4], bfr[4];
#pragma unroll
      for (int i = 0; i < 4; ++i) {
        const int ra = wm * 64 + i * 16 + rl;
        af[i] = *(const bf16x8*)((const char*)ldsA + ra * 128 +
                                 (((kk * 4 + quad) ^ (rl & 7)) * 16));
        const int rb = wn * 64 + i * 16 + rl;
        bfr[i] = *(const bf16x8*)((const char*)ldsB + rb * 128 +
                                  (((kk * 4 + quad) ^ (rl & 7)) * 16));
      }
#pragma unroll
      for (int i = 0; i < 4; ++i)
#pragma unroll
        for (int j = 0; j < 4; ++j)
          acc[i][j] =
              __builtin_amdgcn_mfma_f32_16x16x32_bf16(af[i], bfr[j], acc[i][j], 0, 0, 0);
    }
    __syncthreads();
  }
}

// ===================== QKV projection GEMM ==================================
__global__ __launch_bounds__(256, 2) void gemm_qkv_kernel(
    const bf16* __restrict__ xT, const bf16* __restrict__ Wqkv,
    const float* __restrict__ bq, const float* __restrict__ bk,
    const float* __restrict__ bv, bf16* __restrict__ Q, bf16* __restrict__ Kb,
    bf16* __restrict__ VT) {
  __shared__ bf16 ldsA[128 * 64], ldsB[128 * 64];
  const int tm = blockIdx.x * 128, tn = blockIdx.y * 128;
  f32x4 acc[4][4];
  const f32x4 z = {0.f, 0.f, 0.f, 0.f};
#pragma unroll
  for (int i = 0; i < 4; ++i)
#pragma unroll
    for (int j = 0; j < 4; ++j) acc[i][j] = z;
  gemm_tile_128(xT, Wqkv, tm, tn, ldsA, ldsB, acc);
  const int lane = threadIdx.x & 63, wave = threadIdx.x >> 6;
  const int wm = wave >> 1, wn = wave & 1;
  const int rl = lane & 15, quad = lane >> 4;
  // Q scale folds 1/sqrt(64) * log2(e) so attn uses raw 2^x
  const float QSCALE = 0.18033688011112042f;
#pragma unroll
  for (int j = 0; j < 4; ++j) {
    const int n = tn + wn * 64 + j * 16 + rl;  // 0..3071
    const int which = n >> 10;                 // uniform per block
    const int nl = n & 1023;
    const int h = nl >> 6, d = nl & 63;
    const float bias = (which == 0 ? bq : which == 1 ? bk : bv)[nl];
#pragma unroll
    for (int i = 0; i < 4; ++i) {
      const int m0 = tm + wm * 64 + i * 16 + quad * 4;
      const int b = m0 >> 11, s0 = m0 & 2047;
      const size_t bh = (size_t)(b * 16 + h);
      if (which == 2) {
        bf16x4 pk;
#pragma unroll
        for (int r = 0; r < 4; ++r) pk[r] = (bf16)(acc[i][j][r] + bias);
        *(bf16x4*)(VT + ((size_t)bh * 64 + d) * 2048 + s0) = pk;  // V^T packed
      } else {
#pragma unroll
        for (int r = 0; r < 4; ++r) {
          const float v = acc[i][j][r] + bias;
          const int s = s0 + r;
          if (which == 0)
            Q[(bh * 2048 + s) * 64 + d] = (bf16)(v * QSCALE);
          else
            Kb[(bh * 2048 + s) * 64 + d] = (bf16)v;
        }
      }
    }
  }
}

// ===================== flash attention ======================================
// grid (B*H=64, S/256=8): bh%8 = XCD -> each head's K/V pinned to one XCD L2.
// 256 q/block, 64 q/wave, 2 blocks/CU (64 KB LDS). All MFMA K=32.
// S^T = K*Q^T (C rows=keys); P -> per-wave 8 KB LDS (rows=q, 128B, swizzled
// chunk^(rl&7) on BOTH sides: writes 4/bank floor, reads 8/bank floor);
// PV: O = P*V^T with pf as A, vf as B. l via ones-MFMA (C rows match o_acc).
__global__ __launch_bounds__(256, 2) void attn_kernel(const bf16* __restrict__ Q,
                                                      const bf16* __restrict__ Kb,
                                                      const bf16* __restrict__ VT,
                                                      bf16* __restrict__ AO) {
  __shared__ __align__(16) char smem[65536];
  char* ldsK = smem;           // 2 x 8 KB (double buffer)
  char* ldsV = smem + 16384;   // 2 x 8 KB (double buffer)
  char* ldsP = smem + 32768;   // 4 waves x 8 KB
  const int tid = threadIdx.x;
  const int lane = tid & 63, wave = tid >> 6;
  const int rl = lane & 15, quad = lane >> 4;
  const int bh = blockIdx.x;
  const int q0 = blockIdx.y * 256;
  const bf16* Qb = Q + ((size_t)bh * 2048 + q0) * 64;
  const bf16* Kbb = Kb + (size_t)bh * 2048 * 64;
  const bf16* Vb = VT + (size_t)bh * 64 * 2048;
  // staging geometry: 2 x 16B chunks per thread per 8KB tile, rows 128B
  const int o0 = wave * 1024 + lane * 16, o1 = o0 + 4096;
  const int ra = o0 >> 7, rb = o1 >> 7;
  const int ca = (((o0 >> 4) & 7) ^ (ra & 7)) * 16;
  const int cb = (((o1 >> 4) & 7) ^ (rb & 7)) * 16;
  gld16((const char*)Kbb + (size_t)ra * 128 + ca, ldsK + wave * 1024);
  gld16((const char*)Kbb + (size_t)rb * 128 + cb, ldsK + wave * 1024 + 4096);
  gld16((const char*)Vb + (size_t)ra * 4096 + ca, ldsV + wave * 1024);
  gld16((const char*)Vb + (size_t)rb * 4096 + cb, ldsV + wave * 1024 + 4096);
  // Q fragments straight from global (read exactly once; aligned 16B)
  bf16x8 qf[4][2];
#pragma unroll
  for (int i = 0; i < 4; ++i)
#pragma unroll
    for (int ks = 0; ks < 2; ++ks)
      qf[i][ks] =
          *(const bf16x8*)(Qb + (wave * 64 + i * 16 + rl) * 64 + ks * 32 + quad * 8);
  f32x4 o_acc[4][4], lacc[4];  // o_acc[i=q-tile][j=d-tile]
  const f32x4 z = {0.f, 0.f, 0.f, 0.f};
#pragma unroll
  for (int i = 0; i < 4; ++i) {
    lacc[i] = z;
#pragma unroll
    for (int j = 0; j < 4; ++j) o_acc[i][j] = z;
  }
  const bf16 oneb = (bf16)1.0f;
  const bf16x8 onesb = {oneb, oneb, oneb, oneb, oneb, oneb, oneb, oneb};
  char* Pw = ldsP + wave * 8192;  // per-wave private P: 64 q-rows x 128 B
  int buf = 0;
  for (int kt = 0; kt < 2048; kt += 64, buf ^= 1) {
    __syncthreads();  // K/V[buf] landed (vmcnt drain); buf^1 free for prefetch
    if (kt + 64 < 2048) {
      const int nb = (buf ^ 1) * 8192;
      gld16((const char*)Kbb + (size_t)(kt + 64 + ra) * 128 + ca, ldsK + nb + wave * 1024);
      gld16((const char*)Kbb + (size_t)(kt + 64 + rb) * 128 + cb,
            ldsK + nb + wave * 1024 + 4096);
      gld16((const char*)Vb + (size_t)ra * 4096 + (size_t)(kt + 64) * 2 + ca,
            ldsV + nb + wave * 1024);
      gld16((const char*)Vb + (size_t)rb * 4096 + (size_t)(kt + 64) * 2 + cb,
            ldsV + nb + wave * 1024 + 4096);
    }
    const char* Kbase = ldsK + buf * 8192;
    const char* Vbase = ldsV + buf * 8192;
    // S^T per 16-key group jk; exp; packed b64 write into P (rows = q)
#pragma unroll
    for (int jk = 0; jk < 4; ++jk) {
      const bf16x8 kf0 =
          *(const bf16x8*)(Kbase + (jk * 16 + rl) * 128 + ((quad ^ (rl & 7)) * 16));
      const bf16x8 kf1 =
          *(const bf16x8*)(Kbase + (jk * 16 + rl) * 128 + (((4 + quad) ^ (rl & 7)) * 16));
#pragma unroll
      for (int i = 0; i < 4; ++i) {
        f32x4 s = z;
        s = __builtin_amdgcn_mfma_f32_16x16x32_bf16(kf0, qf[i][0], s, 0, 0, 0);
        s = __builtin_amdgcn_mfma_f32_16x16x32_bf16(kf1, qf[i][1], s, 0, 0, 0);
        // lane: q = i*16+rl (col), keys jk*16+quad*4+r (rows) -> b64 write:
        // row i*16+rl, logical chunk16 = jk*2+(quad>>1), ^(rl&7), half quad&1
        bf16x4 pk;
#pragma unroll
        for (int r = 0; r < 4; ++r) pk[r] = (bf16)exp2_fast(s[r]);
        *(bf16x4*)(Pw + (i * 16 + rl) * 128 + (((jk * 2 + (quad >> 1)) ^ (rl & 7)) * 16) +
                   (quad & 1) * 8) = pk;
      }
    }
    // same-wave visibility only — P buffer is wave-private
    asm volatile("s_waitcnt lgkmcnt(0)" ::: "memory");
    // O += P V ; l += P 1   (all K=32; pf = A rows q, vf = B rows d)
#pragma unroll
    for (int ks = 0; ks < 2; ++ks) {
      bf16x8 pf[4];
#pragma unroll
      for (int i = 0; i < 4; ++i)
        pf[i] = *(const bf16x8*)(Pw + (i * 16 + rl) * 128 +
                                 (((ks * 4 + quad) ^ (rl & 7)) * 16));
#pragma unroll
      for (int i = 0; i < 4; ++i)
        lacc[i] = __builtin_amdgcn_mfma_f32_16x16x32_bf16(pf[i], onesb, lacc[i], 0, 0, 0);
#pragma unroll
      for (int j = 0; j < 4; ++j) {
        const bf16x8 vf = *(const bf16x8*)(Vbase + (j * 16 + rl) * 128 +
                                           (((ks * 4 + quad) ^ (rl & 7)) * 16));
#pragma unroll
        for (int i = 0; i < 4; ++i)
          o_acc[i][j] =
              __builtin_amdgcn_mfma_f32_16x16x32_bf16(pf[i], vf, o_acc[i][j], 0, 0, 0);
      }
    }
  }
  // lacc rows (quad*4+r) match o_acc rows exactly — per-lane rcp, no shuffles
  const int b = bh >> 4, h = bh & 15;
#pragma unroll
  for (int i = 0; i < 4; ++i) {
    f32x4 linv;
#pragma unroll
    for (int r = 0; r < 4; ++r) linv[r] = __builtin_amdgcn_rcpf(lacc[i][r]);
#pragma unroll
    for (int j = 0; j < 4; ++j)
#pragma unroll
      for (int r = 0; r < 4; ++r) {
        const int s = q0 + wave * 64 + i * 16 + quad * 4 + r;
        const int d = h * 64 + j * 16 + rl;
        AO[((size_t)b * 2048 + s) * 1024 + d] = (bf16)(o_acc[i][j][r] * linv[r]);
      }
  }
}

// ===================== output projection GEMM (transposed fp32 store) =======
__global__ __launch_bounds__(256, 2) void gemm_out_kernel(const bf16* __restrict__ AO,
                                                          const bf16* __restrict__ WoB,
                                                          const float* __restrict__ bo,
                                                          float* __restrict__ out) {
  __shared__ bf16 ldsA[128 * 64], ldsB[128 * 64];
  const int tm = blockIdx.x * 128, tn = blockIdx.y * 128;
  f32x4 acc[4][4];
  const f32x4 z = {0.f, 0.f, 0.f, 0.f};
#pragma unroll
  for (int i = 0; i < 4; ++i)
#pragma unroll
    for (int j = 0; j < 4; ++j) acc[i][j] = z;
  gemm_tile_128(AO, WoB, tm, tn, ldsA, ldsB, acc);
  const int lane = threadIdx.x & 63, wave = threadIdx.x >> 6;
  const int wm = wave >> 1, wn = wave & 1;
  const int rl = lane & 15, quad = lane >> 4;
#pragma unroll
  for (int j = 0; j < 4; ++j) {
    const int n = tn + wn * 64 + j * 16 + rl;  // = d
    const float bias = bo[n];
#pragma unroll
    for (int i = 0; i < 4; ++i) {
      const int m0 = tm + wm * 64 + i * 16 + quad * 4;
      const int b = m0 >> 11, s = m0 & 2047;
      f32x4 v = acc[i][j];
      v[0] += bias;
      v[1] += bias;
      v[2] += bias;
      v[3] += bias;
      *(f32x4*)(out + ((size_t)(b * 1024 + n)) * 2048 + s) = v;
    }
  }
}

extern "C" void kernel_launch(void* const* d_in, const int* in_sizes, int n_in,
                              void* d_out, int out_size, void* d_ws, size_t ws_size,
                              hipStream_t stream) {
  const float* x = (const float*)d_in[0];
  const float* Wq = (const float*)d_in[1];
  const float* bq = (const float*)d_in[2];
  const float* Wk = (const float*)d_in[3];
  const float* bk = (const float*)d_in[4];
  const float* Wv = (const float*)d_in[5];
  const float* bv = (const float*)d_in[6];
  const float* Wo = (const float*)d_in[7];
  const float* bo = (const float*)d_in[8];
  float* out = (float*)d_out;

  char* p = (char*)d_ws;
  bf16* xT = (bf16*)p;
  p += (size_t)NM * ND * 2;  // 16 MiB
  bf16* Wqkv = (bf16*)p;
  p += (size_t)3 * ND * ND * 2;  // 6 MiB
  bf16* WoB = (bf16*)p;
  p += (size_t)ND * ND * 2;  // 2 MiB
  bf16* Qb = (bf16*)p;
  p += (size_t)NM * ND * 2;
  bf16* Kbf = (bf16*)p;
  p += (size_t)NM * ND * 2;
  bf16* VTb = (bf16*)p;
  p += (size_t)NM * ND * 2;
  bf16* AO = xT;  // alias: xT fully consumed by gemm_qkv before attn writes AO

  prep_x_kernel<<<dim3(NS / 32, ND / 32, NB), dim3(32, 8), 0, stream>>>(x, xT);
  prep_w_kernel<<<dim3(4096), dim3(256), 0, stream>>>(Wq, Wk, Wv, Wo, Wqkv, WoB);
  gemm_qkv_kernel<<<dim3(NM / 128, 3072 / 128), dim3(256), 0, stream>>>(
      xT, Wqkv, bq, bk, bv, Qb, Kbf, VTb);
  attn_kernel<<<dim3(NB * NH, NS / 256), dim3(256), 0, stream>>>(Qb, Kbf, VTb, AO);
  gemm_out_kernel<<<dim3(NM / 128, ND / 128), dim3(256), 0, stream>>>(AO, WoB, bo, out);
}